// Round 5
// baseline (1045.456 us; speedup 1.0000x reference)
//
#include <hip/hip_runtime.h>
#include <math.h>
#include <stdint.h>

// Problem constants: B=16, S=256, E=256, H=256, V=50000, L=9
#define BB 16
#define SS 256
#define LL 9
#define ROWS 4096
#define HP 272         // bytes per batch row of H in LDS (fp8)

typedef __attribute__((ext_vector_type(8))) short short8;   // 8 bf16
typedef __attribute__((ext_vector_type(4))) float f32x4;    // MFMA acc
typedef __attribute__((ext_vector_type(8))) int i32x8;      // 32B MX fragment

#define HSCALE 256.0f
#define LOG2E  1.44269504f
// per-gate weight pack constants: i,f,o = -LOG2E*1024; g = +2*LOG2E*512
#define WCONST 1477.3199f
#define SCALE_ONE 0x7F7F7F7Fu
#define SCALE_IFO 0x6D6D6D6Du
#define SCALE_G   0x6E6E6E6Eu

__device__ __forceinline__ unsigned short f2bf(float f) {
  unsigned u = __float_as_uint(f);
  return (unsigned short)((u + 0x7FFF + ((u >> 16) & 1)) >> 16);  // RNE
}
__device__ __forceinline__ float bf2f(unsigned short s) {
  return __uint_as_float(((unsigned)s) << 16);
}

// async global->LDS, 16B per lane; LDS dest = (wave-uniform base) + lane*16
__device__ __forceinline__ void gl2lds16(const void* g, void* l) {
  __builtin_amdgcn_global_load_lds(
      (const __attribute__((address_space(1))) void*)g,
      (__attribute__((address_space(3))) void*)l, 16, 0, 0);
}

// LDS-only barrier: drains DS ops (lgkmcnt) but NOT global stores/loads
// (vmcnt). Measured neutral vs __syncthreads (R4 == R1), kept because it can
// only help. Trailing memory-clobber keeps next step's ds_read below the
// barrier without pinning VALU scheduling (sched_barrier(0) cost 230cyc, R2).
__device__ __forceinline__ void barrier_lds_only() {
  asm volatile("s_waitcnt lgkmcnt(0)" ::: "memory");
  __builtin_amdgcn_s_barrier();
  asm volatile("" ::: "memory");
}

// ---------------------------------------------------------------------------
// Embedding gather -> bf16 x0 [4096][256]
__global__ __launch_bounds__(256) void embed_bf16(
    const int* __restrict__ ids, const float* __restrict__ emb,
    unsigned short* __restrict__ x0) {
  int row = blockIdx.x;
  int id = ids[row];
  x0[(size_t)row * 256 + threadIdx.x] = f2bf(emb[(size_t)id * 256 + threadIdx.x]);
}

// ---------------------------------------------------------------------------
// Pack w_hh (ALL layers) into fp8 e4m3 MX B-fragments (K=128), log-domain consts.
__global__ __launch_bounds__(64) void pack_whh_mx(
    const float* __restrict__ w, unsigned* __restrict__ wfrag) {
  int nb = blockIdx.x, ks2 = blockIdx.y, z = blockIdx.z;  // z = layer*2+dir
  int lane = threadIdx.x, qq = lane >> 4, col = lane & 15;
  int g = nb >> 4;
  float csc = (g == 2) ? WCONST : -WCONST;
  const float* wp = w + (size_t)z * 1024 * 256 + (size_t)(nb * 16 + col) * 256 +
                    ks2 * 128 + qq * 32;
  unsigned* op = wfrag + (((size_t)(z * 64 + nb) * 2 + ks2) * 64 + lane) * 8;
#pragma unroll
  for (int u = 0; u < 8; ++u) {
    float v0 = wp[u * 4 + 0] * csc, v1 = wp[u * 4 + 1] * csc;
    float v2 = wp[u * 4 + 2] * csc, v3 = wp[u * 4 + 3] * csc;
    unsigned pk = __builtin_amdgcn_cvt_pk_fp8_f32(v0, v1, 0, false);
    pk = __builtin_amdgcn_cvt_pk_fp8_f32(v2, v3, pk, true);
    op[u] = pk;
  }
}

// ---------------------------------------------------------------------------
// biasPF[l][dir][n'] = (b_ih[n]+b_hh[n]) * cg(n'),  n' = j*4+g, n = g*256+j
__global__ __launch_bounds__(256) void bias_perm(
    const float* __restrict__ b2, float* __restrict__ biasPF) {
  int i = blockIdx.x * 256 + threadIdx.x;  // 0..8191
  int l = i >> 11, r = i & 2047;
  int dir = r >> 10, np = r & 1023;
  int n = ((np & 3) << 8) + (np >> 2);
  float cg = ((np & 3) == 2) ? (2.0f * LOG2E) : (-LOG2E);
  biasPF[i] = (b2[l * 4096 + dir * 2048 + n] + b2[l * 4096 + dir * 2048 + 1024 + n]) * cg;
}

// ---------------------------------------------------------------------------
// Pre-convert W_ih (all layers) to bf16, gate-permuted rows, cg folded:
// wp[l][dir][n'][k] = bf16( W[l][dir][nphys(n')][k] * cg(n') )
__global__ __launch_bounds__(256) void prep_wih(
    const float* __restrict__ w_l0, const float* __restrict__ w_rest,
    unsigned short* __restrict__ wp, const long* __restrict__ woff_dummy) {
  int l = blockIdx.z;
  int Ksh = l ? 9 : 8;
  int K = 1 << Ksh;
  long total = (long)2 * 1024 * K;
  long idx = (long)blockIdx.x * 256 + threadIdx.x;
  if (idx >= total) return;
  int k = (int)(idx & (K - 1));
  long r = idx >> Ksh;
  int np = (int)(r & 1023), dir = (int)(r >> 10);
  int nph = ((np & 3) << 8) + (np >> 2);
  float cg = ((np & 3) == 2) ? (2.0f * LOG2E) : (-LOG2E);
  const float* src = l ? (w_rest + (size_t)(l - 1) * 2 * 1024 * 512) : w_l0;
  size_t off = l ? (524288 + (size_t)(l - 1) * 1048576) : 0;
  wp[off + idx] = f2bf(src[((size_t)dir * 1024 + nph) * K + k] * cg);
}

// ---------------------------------------------------------------------------
// m97-style bf16 MFMA GEMM with global_load_lds staging.
// xgP[dir][row][n'] = sum_k A[row][k]*BP[dir][n'][k] + biasPF  (cg pre-folded)
// Block 512 thr (8 waves), tile M128 x N128, BK=32, 2 blocks/CU.
__global__ __launch_bounds__(512) void gemm_xg128(
    const unsigned short* __restrict__ A, int K,
    const unsigned short* __restrict__ BP,
    const float* __restrict__ biasPF,
    unsigned short* __restrict__ xgP) {
  int dir = blockIdx.z;
  int n0 = blockIdx.x * 128, m0 = blockIdx.y * 128;
  int tid = threadIdx.x;
  int wv = tid >> 6, lane = tid & 63, quad = lane >> 4, col = lane & 15;
  __shared__ unsigned short As[128 * 32];
  __shared__ unsigned short Bs[128 * 32];
  const unsigned short* Bw = BP + (size_t)dir * 1024 * K;

  // staging: wave wv stages rows [16wv,16wv+16) of A and B; lane -> (row,kc)
  int srow = lane >> 2;
  int scol = (lane & 3) * 8;
  const unsigned short* ga = A + (size_t)(m0 + wv * 16 + srow) * K + scol;
  const unsigned short* gb = Bw + (size_t)(n0 + wv * 16 + srow) * K + scol;
  unsigned short* lA = &As[wv * 512];   // 1 KB per wave slice
  unsigned short* lB = &Bs[wv * 512];

  int wm = wv & 1;       // M 64-half
  int wn = wv >> 1;      // N 32-slice
  f32x4 acc[4][2];
#pragma unroll
  for (int mt = 0; mt < 4; ++mt)
#pragma unroll
    for (int nt = 0; nt < 2; ++nt) acc[mt][nt] = (f32x4){0.f, 0.f, 0.f, 0.f};

  for (int k0 = 0; k0 < K; k0 += 32) {
    __syncthreads();               // prior iteration's fragment reads done
    gl2lds16(ga, lA);
    gl2lds16(gb, lB);
    ga += 32; gb += 32;
    __syncthreads();               // drains vmcnt -> LDS data visible
    short8 bf0 = *(const short8*)&Bs[(wn * 32 + col) * 32 + quad * 8];
    short8 bf1 = *(const short8*)&Bs[(wn * 32 + 16 + col) * 32 + quad * 8];
#pragma unroll
    for (int mt = 0; mt < 4; ++mt) {
      short8 af = *(const short8*)&As[(wm * 64 + mt * 16 + col) * 32 + quad * 8];
      acc[mt][0] = __builtin_amdgcn_mfma_f32_16x16x32_bf16(af, bf0, acc[mt][0], 0, 0, 0);
      acc[mt][1] = __builtin_amdgcn_mfma_f32_16x16x32_bf16(af, bf1, acc[mt][1], 0, 0, 0);
    }
  }

#pragma unroll
  for (int nt = 0; nt < 2; ++nt) {
    int np = n0 + wn * 32 + nt * 16 + col;
    float bia = biasPF[dir * 1024 + np];
#pragma unroll
    for (int mt = 0; mt < 4; ++mt) {
#pragma unroll
      for (int r = 0; r < 4; ++r) {
        int row = m0 + wm * 64 + mt * 16 + quad * 4 + r;
        xgP[((size_t)dir * ROWS + row) * 1024 + np] = f2bf(acc[mt][nt][r] + bia);
      }
    }
  }
}

// ---------------------------------------------------------------------------
// MX-fp8 (K=128) MFMA LSTM recurrence.
// 8 blocks x 1024 threads (16 waves, 4 waves/SIMD), 4 batches per block
// packed into M rows (4 copies each). Each wave owns 16 hidden units (one
// nb 16-col block per gate). xq injected via MFMA C-operand; xq prefetched
// 1 step ahead. Per-step LDS-only barrier.
// R5: (a) the two K-half MFMAs per gate use INDEPENDENT accumulators
// (accL C-injects xq, accH uses a loop-invariant ZERO4 quad) so all 8
// MFMAs per wave issue back-to-back and the last result lands one chain-
// latency earlier; (b) the global xout store is deferred to the next
// step's head (ds_read-latency shadow), off the pre-barrier tail.
__global__ __launch_bounds__(1024, 4) void lstm_mx(
    const unsigned short* __restrict__ xgP,   // [2][4096][1024] bf16 n'=j*4+g
    const unsigned* __restrict__ wfrag,       // layer slice: [2][64][2][64][8] dw
    unsigned short* __restrict__ xout) {      // [4096][512] bf16
  int dir = blockIdx.x & 1;
  int bg = blockIdx.x >> 1;            // 0..3 -> batches bg*4 .. bg*4+3
  int tid = threadIdx.x;
  int wv = tid >> 6, lane = tid & 63;
  int quad = lane >> 4, col = lane & 15;

  __shared__ __align__(16) unsigned char Hfrag[2][4 * HP];

  {
    // zero Hfrag[0] (4*HP = 1088 B = 272 ints)
    int* hz = (int*)&Hfrag[0][0];
    for (int i = tid; i < HP; i += 1024) hz[i] = 0;
  }

  // weight fragments: wave wv covers nb = g*16 + wv (16 hidden units x 4 gates)
  i32x8 wf[4][2];
#pragma unroll
  for (int g = 0; g < 4; ++g) {
    int nb = g * 16 + wv;
#pragma unroll
    for (int ks2 = 0; ks2 < 2; ++ks2)
      wf[g][ks2] = *(const i32x8*)(wfrag +
          (((size_t)(dir * 64 + nb) * 2 + ks2) * 64 + lane) * 8);
  }

  // A-fragment: row = lane&15 -> batch = row>>2 (4 copies), k-chunk = quad*32
  int aoff = ((lane & 15) >> 2) * HP + (lane >> 4) * 32;

  int j = 16 * wv + col;               // this thread's hidden unit
  int b = bg * 4 + quad;               // this thread's batch
  int pos0 = dir ? (SS - 1) : 0;
  int dstep = dir ? -1 : 1;
  const unsigned short* xq_ptr =
      xgP + ((size_t)dir * ROWS + (size_t)b * SS + pos0) * 1024 + j * 4;
  unsigned short* xo_ptr = xout + ((size_t)b * SS + pos0) * 512 + dir * 256 + j;
  int xq_d = dstep * 1024;
  int xo_d = dstep * 512;
  int hw = quad * HP + j;              // this thread's H byte slot

  const f32x4 ZERO4 = (f32x4){0.f, 0.f, 0.f, 0.f};  // loop-invariant C quad

  float Cp = 0.f;                 // C' = 2*LOG2E * c
  int cur = 0;
  unsigned short ph = 0;
  unsigned short* xo_prev = xo_ptr;
  // prefetch step 0 gate inputs
  ushort4 xq_n = *(const ushort4*)xq_ptr;
  xq_ptr += xq_d;
  __syncthreads();                // initial full sync (zero-init visible)

  for (int t = 0; t < SS; ++t) {
    // deferred xout store from step t-1: lands in the ds_read-latency shadow
    if (t) *xo_prev = ph;
    ushort4 xq = xq_n;
    // prefetch t+1 (t=255 over-read stays inside the 16 MB xgP; value unused)
    xq_n = *(const ushort4*)xq_ptr;
    xq_ptr += xq_d;

    i32x8 af0 = *(const i32x8*)&Hfrag[cur][aoff];
    i32x8 af1 = *(const i32x8*)&Hfrag[cur][aoff + 128];

    // independent accumulators per gate: accL C-injects xq (lane's [0] is
    // row quad*4, col), accH starts from the shared ZERO4 quad.
    f32x4 accL[4], accH[4];
    accL[0] = (f32x4){bf2f(xq.x), 0.f, 0.f, 0.f};
    accL[1] = (f32x4){bf2f(xq.y), 0.f, 0.f, 0.f};
    accL[2] = (f32x4){bf2f(xq.z), 0.f, 0.f, 0.f};
    accL[3] = (f32x4){bf2f(xq.w), 0.f, 0.f, 0.f};
#pragma unroll
    for (int g = 0; g < 4; ++g) {
      unsigned sb = (g == 2) ? SCALE_G : SCALE_IFO;
      accL[g] = __builtin_amdgcn_mfma_scale_f32_16x16x128_f8f6f4(
          af0, wf[g][0], accL[g], 0, 0, 0, SCALE_ONE, 0, sb);
      accH[g] = __builtin_amdgcn_mfma_scale_f32_16x16x128_f8f6f4(
          af1, wf[g][1], ZERO4, 0, 0, 0, SCALE_ONE, 0, sb);
    }

    int nxt = cur ^ 1;
    float gi = accL[0][0] + accH[0][0];
    float gf = accL[1][0] + accH[1][0];
    float gt = accL[2][0] + accH[2][0];
    float go = accL[3][0] + accH[3][0];
    float si = __builtin_amdgcn_rcpf(1.0f + __builtin_amdgcn_exp2f(gi));
    float sf = __builtin_amdgcn_rcpf(1.0f + __builtin_amdgcn_exp2f(gf));
    float so = __builtin_amdgcn_rcpf(1.0f + __builtin_amdgcn_exp2f(go));
    float rg = __builtin_amdgcn_rcpf(1.0f + __builtin_amdgcn_exp2f(gt));
    float tg2 = fmaf(-4.0f * LOG2E, rg, 2.0f * LOG2E);
    Cp = fmaf(sf, Cp, si * tg2);
    float rc = __builtin_amdgcn_rcpf(1.0f + __builtin_amdgcn_exp2f(Cp));
    float h = so * fmaf(-2.0f, rc, 1.0f);

    // H to LDS (critical path: ds_write -> lgkm -> barrier); xout deferred.
    unsigned pk = __builtin_amdgcn_cvt_pk_fp8_f32(h * HSCALE, h * HSCALE, 0, false);
    Hfrag[nxt][hw] = (unsigned char)(pk & 0xFF);
    ph = f2bf(h);
    xo_prev = xo_ptr;
    xo_ptr += xo_d;

    barrier_lds_only();
    cur = nxt;
  }
  *xo_prev = ph;
}

// ---------------------------------------------------------------------------
// LayerNorm + 9-way linear. One wave per row. X is bf16 [4096][512].
__global__ __launch_bounds__(64) void ln_logits(
    const unsigned short* __restrict__ X, const float* __restrict__ g,
    const float* __restrict__ bt, const float* __restrict__ W,
    const float* __restrict__ lb, float* __restrict__ out) {
  int row = blockIdx.x;
  int lane = threadIdx.x;
  const unsigned short* x = X + (size_t)row * 512;
  float v[8];
  float s = 0.f, s2 = 0.f;
#pragma unroll
  for (int i = 0; i < 8; ++i) {
    v[i] = bf2f(x[lane + 64 * i]);
    s += v[i];
    s2 += v[i] * v[i];
  }
#pragma unroll
  for (int off = 32; off; off >>= 1) {
    s += __shfl_down(s, off, 64);
    s2 += __shfl_down(s2, off, 64);
  }
  s = __shfl(s, 0, 64);
  s2 = __shfl(s2, 0, 64);
  float mu = s * (1.f / 512.f);
  float var = s2 * (1.f / 512.f) - mu * mu;
  float rstd = rsqrtf(var + 1e-5f);
  float y[8];
#pragma unroll
  for (int i = 0; i < 8; ++i) {
    int e = lane + 64 * i;
    y[i] = (v[i] - mu) * rstd * g[e] + bt[e];
  }
  for (int l = 0; l < LL; ++l) {
    float p = 0.f;
#pragma unroll
    for (int i = 0; i < 8; ++i) p += y[i] * W[(size_t)l * 512 + lane + 64 * i];
#pragma unroll
    for (int off = 32; off; off >>= 1) p += __shfl_down(p, off, 64);
    if (lane == 0) out[(size_t)row * LL + l] = p + lb[l];
  }
}

// ---------------------------------------------------------------------------
// CRF numerator + denominator + loss. One block of 256 threads.
__global__ __launch_bounds__(256) void crf_kernel(
    const float* __restrict__ logits, const int* __restrict__ labels,
    const int* __restrict__ mask, const float* __restrict__ cs,
    const float* __restrict__ ce, const float* __restrict__ ct,
    float* __restrict__ loss_out) {
  __shared__ float trans[9][12];
  __shared__ float alpha[2][BB][12];
  __shared__ float numsh[BB];
  __shared__ float res[BB];
  int tid = threadIdx.x;
  int b = tid >> 4;
  int i = tid & 15;
  if (tid < 81) trans[tid / 9][tid % 9] = ct[tid];
  __syncthreads();
  const float* lg = logits + (size_t)b * SS * LL;
  const int* lbp = labels + (size_t)b * SS;
  const int* mk = mask + (size_t)b * SS;

  float np = 0.f;
  int msum = 0;
  for (int t = i; t < SS; t += 16) {
    msum += mk[t];
    if (t == 0) {
      int l0 = lbp[0];
      np += cs[l0] + lg[l0];
    } else {
      float m = (float)mk[t];
      np += (trans[lbp[t - 1]][lbp[t]] + lg[(size_t)t * LL + lbp[t]]) * m;
    }
  }
#pragma unroll
  for (int off = 8; off; off >>= 1) {
    np += __shfl_down(np, off, 16);
    msum += __shfl_down(msum, off, 16);
  }
  if (i == 0) {
    int last = msum - 1;
    numsh[b] = np + ce[lbp[last]];
  }

  if (i < LL) alpha[0][b][i] = cs[i] + lg[i];
  int cur = 0;
  for (int t = 1; t < SS; ++t) {
    if (i < LL) {
      float e = lg[(size_t)t * LL + i];
      float av[9];
      float mmax = -1e30f;
#pragma unroll
      for (int p = 0; p < LL; ++p) {
        float vv = alpha[cur][b][p] + trans[p][i];
        av[p] = vv;
        mmax = fmaxf(mmax, vv);
      }
      float ssum = 0.f;
#pragma unroll
      for (int p = 0; p < LL; ++p) ssum += __expf(av[p] - mmax);
      float anew = e + mmax + logf(ssum);
      float aold = alpha[cur][b][i];
      alpha[cur ^ 1][b][i] = (mk[t] > 0) ? anew : aold;
    }
    cur ^= 1;
  }
  if (i == 0) {
    float arr[9];
    float m2 = -1e30f;
#pragma unroll
    for (int cc = 0; cc < LL; ++cc) {
      arr[cc] = alpha[cur][b][cc] + ce[cc];
      m2 = fmaxf(m2, arr[cc]);
    }
    float ssd = 0.f;
#pragma unroll
    for (int cc = 0; cc < LL; ++cc) ssd += __expf(arr[cc] - m2);
    float denom = m2 + logf(ssd);
    res[b] = numsh[b] - denom;
  }
  __syncthreads();
  if (tid == 0) {
    float Lsum = 0.f;
    for (int b2 = 0; b2 < BB; ++b2) Lsum += res[b2];
    loss_out[0] = -Lsum;
  }
}

// ---------------------------------------------------------------------------
extern "C" void kernel_launch(void* const* d_in, const int* in_sizes, int n_in,
                              void* d_out, int out_size, void* d_ws, size_t ws_size,
                              hipStream_t stream) {
  const int* input_ids = (const int*)d_in[0];
  const int* attn_mask = (const int*)d_in[1];
  const int* labels = (const int*)d_in[2];
  const float* embedding = (const float*)d_in[3];
  const float* w_ih_l0 = (const float*)d_in[4];
  const float* w_ih_rest = (const float*)d_in[5];
  const float* w_hh = (const float*)d_in[6];
  const float* bvec = (const float*)d_in[7];
  const float* ln_g = (const float*)d_in[8];
  const float* ln_b = (const float*)d_in[9];
  const float* lin_w = (const float*)d_in[10];
  const float* lin_b = (const float*)d_in[11];
  const float* crf_start = (const float*)d_in[12];
  const float* crf_end = (const float*)d_in[13];
  const float* crf_trans = (const float*)d_in[14];
  float* out = (float*)d_out;
  char* base = (char*)d_ws;

  unsigned short* x0    = (unsigned short*)(base);                        // 2 MB
  unsigned short* xoutA = (unsigned short*)(base + (2u << 20));           // 4 MB
  unsigned short* xoutB = (unsigned short*)(base + (6u << 20));           // 4 MB
  unsigned short* xgP   = (unsigned short*)(base + (10u << 20));          // 16 MB
  unsigned*       wfrag = (unsigned*)(base + (26u << 20));                // 2 MB
  float*          biasPF= (float*)(base + (28u << 20));                   // 32 KB
  unsigned short* wihP  = (unsigned short*)(base + (29u << 20));          // 7 MB

  embed_bf16<<<ROWS, 256, 0, stream>>>(input_ids, embedding, x0);
  pack_whh_mx<<<dim3(64, 2, 8), 64, 0, stream>>>(w_hh, wfrag);
  bias_perm<<<32, 256, 0, stream>>>(bvec, biasPF);
  prep_wih<<<dim3(4096, 1, 4), 256, 0, stream>>>(w_ih_l0, w_ih_rest, wihP, nullptr);

  // wihP per-layer offsets (ushorts): l0=0, l1=524288, l2=1572864, l3=2621440
  const size_t WOFF[4] = {0, 524288, 1572864, 2621440};

  const unsigned short* cur = x0;
  unsigned short* nxt = xoutA;
  for (int l = 0; l < 4; ++l) {
    int K = l ? 512 : 256;
    gemm_xg128<<<dim3(8, 32, 2), 512, 0, stream>>>(
        cur, K, wihP + WOFF[l], biasPF + (size_t)l * 2048, xgP);
    lstm_mx<<<8, 1024, 0, stream>>>(xgP, wfrag + (size_t)l * 131072, nxt);
    cur = nxt;
    nxt = (nxt == xoutA) ? xoutB : xoutA;
  }

  ln_logits<<<ROWS, 64, 0, stream>>>(cur, ln_g, ln_b, lin_w, lin_b, out);
  crf_kernel<<<1, 256, 0, stream>>>(out, labels, attn_mask, crf_start, crf_end,
                                    crf_trans, out + (size_t)ROWS * LL);
}

// Round 6
// 1000.531 us; speedup vs baseline: 1.0449x; 1.0449x over previous
//
#include <hip/hip_runtime.h>
#include <math.h>
#include <stdint.h>

// Problem constants: B=16, S=256, E=256, H=256, V=50000, L=9
#define BB 16
#define SS 256
#define LL 9
#define ROWS 4096
#define HP 272         // bytes per batch row of H in LDS (fp8)

typedef __attribute__((ext_vector_type(8))) short short8;   // 8 bf16
typedef __attribute__((ext_vector_type(4))) float f32x4;    // MFMA acc
typedef __attribute__((ext_vector_type(8))) int i32x8;      // 32B MX fragment

#define HSCALE 256.0f
#define LOG2E  1.44269504f
// per-gate weight pack constants: i,f,o = -LOG2E*1024; g = +2*LOG2E*512
#define WCONST 1477.3199f
#define SCALE_ONE 0x7F7F7F7Fu
#define SCALE_IFO 0x6D6D6D6Du
#define SCALE_G   0x6E6E6E6Eu

__device__ __forceinline__ unsigned short f2bf(float f) {
  unsigned u = __float_as_uint(f);
  return (unsigned short)((u + 0x7FFF + ((u >> 16) & 1)) >> 16);  // RNE
}
__device__ __forceinline__ float bf2f(unsigned short s) {
  return __uint_as_float(((unsigned)s) << 16);
}

// async global->LDS, 16B per lane; LDS dest = (wave-uniform base) + lane*16
__device__ __forceinline__ void gl2lds16(const void* g, void* l) {
  __builtin_amdgcn_global_load_lds(
      (const __attribute__((address_space(1))) void*)g,
      (__attribute__((address_space(3))) void*)l, 16, 0, 0);
}

// LDS-only barrier: drains DS ops (lgkmcnt) but NOT global stores/loads
// (vmcnt). Measured neutral vs __syncthreads (R4 == R1); kept. Trailing
// memory-clobber keeps next step's ds_read below the barrier without
// pinning VALU scheduling (sched_barrier(0) cost 230 cyc/step in R2).
__device__ __forceinline__ void barrier_lds_only() {
  asm volatile("s_waitcnt lgkmcnt(0)" ::: "memory");
  __builtin_amdgcn_s_barrier();
  asm volatile("" ::: "memory");
}

// ---------------------------------------------------------------------------
// Embedding gather -> bf16 x0 [4096][256]
__global__ __launch_bounds__(256) void embed_bf16(
    const int* __restrict__ ids, const float* __restrict__ emb,
    unsigned short* __restrict__ x0) {
  int row = blockIdx.x;
  int id = ids[row];
  x0[(size_t)row * 256 + threadIdx.x] = f2bf(emb[(size_t)id * 256 + threadIdx.x]);
}

// ---------------------------------------------------------------------------
// Pack w_hh (ALL layers) into fp8 e4m3 MX B-fragments (K=128), log-domain consts.
__global__ __launch_bounds__(64) void pack_whh_mx(
    const float* __restrict__ w, unsigned* __restrict__ wfrag) {
  int nb = blockIdx.x, ks2 = blockIdx.y, z = blockIdx.z;  // z = layer*2+dir
  int lane = threadIdx.x, qq = lane >> 4, col = lane & 15;
  int g = nb >> 4;
  float csc = (g == 2) ? WCONST : -WCONST;
  const float* wp = w + (size_t)z * 1024 * 256 + (size_t)(nb * 16 + col) * 256 +
                    ks2 * 128 + qq * 32;
  unsigned* op = wfrag + (((size_t)(z * 64 + nb) * 2 + ks2) * 64 + lane) * 8;
#pragma unroll
  for (int u = 0; u < 8; ++u) {
    float v0 = wp[u * 4 + 0] * csc, v1 = wp[u * 4 + 1] * csc;
    float v2 = wp[u * 4 + 2] * csc, v3 = wp[u * 4 + 3] * csc;
    unsigned pk = __builtin_amdgcn_cvt_pk_fp8_f32(v0, v1, 0, false);
    pk = __builtin_amdgcn_cvt_pk_fp8_f32(v2, v3, pk, true);
    op[u] = pk;
  }
}

// ---------------------------------------------------------------------------
// biasPF[l][dir][n'] = (b_ih[n]+b_hh[n]) * cg(n'),  n' = j*4+g, n = g*256+j
__global__ __launch_bounds__(256) void bias_perm(
    const float* __restrict__ b2, float* __restrict__ biasPF) {
  int i = blockIdx.x * 256 + threadIdx.x;  // 0..8191
  int l = i >> 11, r = i & 2047;
  int dir = r >> 10, np = r & 1023;
  int n = ((np & 3) << 8) + (np >> 2);
  float cg = ((np & 3) == 2) ? (2.0f * LOG2E) : (-LOG2E);
  biasPF[i] = (b2[l * 4096 + dir * 2048 + n] + b2[l * 4096 + dir * 2048 + 1024 + n]) * cg;
}

// ---------------------------------------------------------------------------
// Pre-convert W_ih (all layers) to bf16, gate-permuted rows, cg folded:
// wp[l][dir][n'][k] = bf16( W[l][dir][nphys(n')][k] * cg(n') )
__global__ __launch_bounds__(256) void prep_wih(
    const float* __restrict__ w_l0, const float* __restrict__ w_rest,
    unsigned short* __restrict__ wp, const long* __restrict__ woff_dummy) {
  int l = blockIdx.z;
  int Ksh = l ? 9 : 8;
  int K = 1 << Ksh;
  long total = (long)2 * 1024 * K;
  long idx = (long)blockIdx.x * 256 + threadIdx.x;
  if (idx >= total) return;
  int k = (int)(idx & (K - 1));
  long r = idx >> Ksh;
  int np = (int)(r & 1023), dir = (int)(r >> 10);
  int nph = ((np & 3) << 8) + (np >> 2);
  float cg = ((np & 3) == 2) ? (2.0f * LOG2E) : (-LOG2E);
  const float* src = l ? (w_rest + (size_t)(l - 1) * 2 * 1024 * 512) : w_l0;
  size_t off = l ? (524288 + (size_t)(l - 1) * 1048576) : 0;
  wp[off + idx] = f2bf(src[((size_t)dir * 1024 + nph) * K + k] * cg);
}

// ---------------------------------------------------------------------------
// bf16 MFMA GEMM, 2-phase pipeline (T3 minimum): double-buffered LDS,
// stage NEXT K-tile before computing CURRENT, ONE __syncthreads per iter
// (its vmcnt(0) drains this iter's stage; its barrier protects the buffer
// the stage will overwrite next iter). Old version exposed the full HBM
// latency + 2 barriers per K-step.
// xgP[dir][row][n'] = sum_k A[row][k]*BP[dir][n'][k] + biasPF  (cg pre-folded)
// Block 512 thr (8 waves), tile M128 x N128, BK=32, 2 blocks/CU.
__global__ __launch_bounds__(512) void gemm_xg128(
    const unsigned short* __restrict__ A, int K,
    const unsigned short* __restrict__ BP,
    const float* __restrict__ biasPF,
    unsigned short* __restrict__ xgP) {
  int dir = blockIdx.z;
  int n0 = blockIdx.x * 128, m0 = blockIdx.y * 128;
  int tid = threadIdx.x;
  int wv = tid >> 6, lane = tid & 63, quad = lane >> 4, col = lane & 15;
  __shared__ unsigned short As[2][128 * 32];
  __shared__ unsigned short Bs[2][128 * 32];
  const unsigned short* Bw = BP + (size_t)dir * 1024 * K;

  // staging: wave wv stages rows [16wv,16wv+16) of A and B; lane -> (row,kc)
  int srow = lane >> 2;
  int scol = (lane & 3) * 8;
  const unsigned short* ga = A + (size_t)(m0 + wv * 16 + srow) * K + scol;
  const unsigned short* gb = Bw + (size_t)(n0 + wv * 16 + srow) * K + scol;
  int lofs = wv * 512;   // wave-uniform LDS slice (1 KB)

  int wm = wv & 1;       // M 64-half
  int wn = wv >> 1;      // N 32-slice
  f32x4 acc[4][2];
#pragma unroll
  for (int mt = 0; mt < 4; ++mt)
#pragma unroll
    for (int nt = 0; nt < 2; ++nt) acc[mt][nt] = (f32x4){0.f, 0.f, 0.f, 0.f};

  int nIter = K >> 5;
  // prologue: stage tile 0 into buffer 0
  gl2lds16(ga, &As[0][lofs]);
  gl2lds16(gb, &Bs[0][lofs]);
  ga += 32; gb += 32;
  __syncthreads();               // vmcnt(0) drain + join: buf0 ready

  for (int it = 0; it < nIter; ++it) {
    int cb = it & 1;
    if (it + 1 < nIter) {        // stage next tile first: DMA overlaps compute
      gl2lds16(ga, &As[cb ^ 1][lofs]);
      gl2lds16(gb, &Bs[cb ^ 1][lofs]);
      ga += 32; gb += 32;
    }
    short8 bf0 = *(const short8*)&Bs[cb][(wn * 32 + col) * 32 + quad * 8];
    short8 bf1 = *(const short8*)&Bs[cb][(wn * 32 + 16 + col) * 32 + quad * 8];
#pragma unroll
    for (int mt = 0; mt < 4; ++mt) {
      short8 af = *(const short8*)&As[cb][(wm * 64 + mt * 16 + col) * 32 + quad * 8];
      acc[mt][0] = __builtin_amdgcn_mfma_f32_16x16x32_bf16(af, bf0, acc[mt][0], 0, 0, 0);
      acc[mt][1] = __builtin_amdgcn_mfma_f32_16x16x32_bf16(af, bf1, acc[mt][1], 0, 0, 0);
    }
    __syncthreads();             // next-buf stage complete; cur-buf reads done
  }

#pragma unroll
  for (int nt = 0; nt < 2; ++nt) {
    int np = n0 + wn * 32 + nt * 16 + col;
    float bia = biasPF[dir * 1024 + np];
#pragma unroll
    for (int mt = 0; mt < 4; ++mt) {
#pragma unroll
      for (int r = 0; r < 4; ++r) {
        int row = m0 + wm * 64 + mt * 16 + quad * 4 + r;
        xgP[((size_t)dir * ROWS + row) * 1024 + np] = f2bf(acc[mt][nt][r] + bia);
      }
    }
  }
}

// ---------------------------------------------------------------------------
// MX-fp8 (K=128) MFMA LSTM recurrence. (R4 version, 182.9 us measured —
// structural floor: per-step ~1714 cyc vs 1104-cyc MFMA-issue invariant.
// R2 DPP-gather, R5 acc-split and deferred-store all regressed; reverted.)
// 8 blocks x 1024 threads (16 waves, 4 waves/SIMD), 4 batches per block
// packed into M rows (4 copies each). Each wave owns 16 hidden units (one
// nb 16-col block per gate). xq injected via MFMA C-operand; xq prefetched
// 1 step ahead. Per-step LDS-only barrier. Per-lane ds_write_b8 H-write
// (conflict-free; the 524288 conflicts/dispatch are the af ds_reads'
// inherent 2-way aliasing, accepted).
__global__ __launch_bounds__(1024, 4) void lstm_mx(
    const unsigned short* __restrict__ xgP,   // [2][4096][1024] bf16 n'=j*4+g
    const unsigned* __restrict__ wfrag,       // layer slice: [2][64][2][64][8] dw
    unsigned short* __restrict__ xout) {      // [4096][512] bf16
  int dir = blockIdx.x & 1;
  int bg = blockIdx.x >> 1;            // 0..3 -> batches bg*4 .. bg*4+3
  int tid = threadIdx.x;
  int wv = tid >> 6, lane = tid & 63;
  int quad = lane >> 4, col = lane & 15;

  __shared__ __align__(16) unsigned char Hfrag[2][4 * HP];

  {
    // zero Hfrag[0] (4*HP = 1088 B = 272 ints)
    int* hz = (int*)&Hfrag[0][0];
    for (int i = tid; i < HP; i += 1024) hz[i] = 0;
  }

  // weight fragments: wave wv covers nb = g*16 + wv (16 hidden units x 4 gates)
  i32x8 wf[4][2];
#pragma unroll
  for (int g = 0; g < 4; ++g) {
    int nb = g * 16 + wv;
#pragma unroll
    for (int ks2 = 0; ks2 < 2; ++ks2)
      wf[g][ks2] = *(const i32x8*)(wfrag +
          (((size_t)(dir * 64 + nb) * 2 + ks2) * 64 + lane) * 8);
  }

  // A-fragment: row = lane&15 -> batch = row>>2 (4 copies), k-chunk = quad*32
  int aoff = ((lane & 15) >> 2) * HP + (lane >> 4) * 32;

  int j = 16 * wv + col;               // this thread's hidden unit
  int b = bg * 4 + quad;               // this thread's batch
  int pos0 = dir ? (SS - 1) : 0;
  int dstep = dir ? -1 : 1;
  const unsigned short* xq_ptr =
      xgP + ((size_t)dir * ROWS + (size_t)b * SS + pos0) * 1024 + j * 4;
  unsigned short* xo_ptr = xout + ((size_t)b * SS + pos0) * 512 + dir * 256 + j;
  int xq_d = dstep * 1024;
  int xo_d = dstep * 512;
  int hw = quad * HP + j;              // this thread's H byte slot

  float Cp = 0.f;                 // C' = 2*LOG2E * c
  int cur = 0;
  // prefetch step 0 gate inputs
  ushort4 xq_n = *(const ushort4*)xq_ptr;
  xq_ptr += xq_d;
  __syncthreads();                // initial full sync (zero-init visible)

  for (int t = 0; t < SS; ++t) {
    ushort4 xq = xq_n;
    // prefetch t+1 (t=255 over-read stays inside the 16 MB xgP; value unused)
    xq_n = *(const ushort4*)xq_ptr;
    xq_ptr += xq_d;

    i32x8 af0 = *(const i32x8*)&Hfrag[cur][aoff];
    i32x8 af1 = *(const i32x8*)&Hfrag[cur][aoff + 128];

    // inject xq via C-operand: lane's acc[g][0] is exactly (row=quad*4, col)
    f32x4 acc[4];
    acc[0] = (f32x4){bf2f(xq.x), 0.f, 0.f, 0.f};
    acc[1] = (f32x4){bf2f(xq.y), 0.f, 0.f, 0.f};
    acc[2] = (f32x4){bf2f(xq.z), 0.f, 0.f, 0.f};
    acc[3] = (f32x4){bf2f(xq.w), 0.f, 0.f, 0.f};
#pragma unroll
    for (int g = 0; g < 4; ++g) {
      unsigned sb = (g == 2) ? SCALE_G : SCALE_IFO;
      acc[g] = __builtin_amdgcn_mfma_scale_f32_16x16x128_f8f6f4(
          af0, wf[g][0], acc[g], 0, 0, 0, SCALE_ONE, 0, sb);
      acc[g] = __builtin_amdgcn_mfma_scale_f32_16x16x128_f8f6f4(
          af1, wf[g][1], acc[g], 0, 0, 0, SCALE_ONE, 0, sb);
    }

    int nxt = cur ^ 1;
    float gi = acc[0][0];
    float gf = acc[1][0];
    float gt = acc[2][0];
    float go = acc[3][0];
    float si = __builtin_amdgcn_rcpf(1.0f + __builtin_amdgcn_exp2f(gi));
    float sf = __builtin_amdgcn_rcpf(1.0f + __builtin_amdgcn_exp2f(gf));
    float so = __builtin_amdgcn_rcpf(1.0f + __builtin_amdgcn_exp2f(go));
    float rg = __builtin_amdgcn_rcpf(1.0f + __builtin_amdgcn_exp2f(gt));
    float tg2 = fmaf(-4.0f * LOG2E, rg, 2.0f * LOG2E);
    Cp = fmaf(sf, Cp, si * tg2);
    float rc = __builtin_amdgcn_rcpf(1.0f + __builtin_amdgcn_exp2f(Cp));
    float h = so * fmaf(-2.0f, rc, 1.0f);

    // H to LDS (critical path: ds_write -> lgkm -> barrier), then the
    // fire-and-forget global h out (never drained by the per-step barrier).
    unsigned pk = __builtin_amdgcn_cvt_pk_fp8_f32(h * HSCALE, h * HSCALE, 0, false);
    Hfrag[nxt][hw] = (unsigned char)(pk & 0xFF);
    *xo_ptr = f2bf(h);
    xo_ptr += xo_d;

    barrier_lds_only();
    cur = nxt;
  }
}

// ---------------------------------------------------------------------------
// LayerNorm + 9-way linear. One wave per row. X is bf16 [4096][512].
__global__ __launch_bounds__(64) void ln_logits(
    const unsigned short* __restrict__ X, const float* __restrict__ g,
    const float* __restrict__ bt, const float* __restrict__ W,
    const float* __restrict__ lb, float* __restrict__ out) {
  int row = blockIdx.x;
  int lane = threadIdx.x;
  const unsigned short* x = X + (size_t)row * 512;
  float v[8];
  float s = 0.f, s2 = 0.f;
#pragma unroll
  for (int i = 0; i < 8; ++i) {
    v[i] = bf2f(x[lane + 64 * i]);
    s += v[i];
    s2 += v[i] * v[i];
  }
#pragma unroll
  for (int off = 32; off; off >>= 1) {
    s += __shfl_down(s, off, 64);
    s2 += __shfl_down(s2, off, 64);
  }
  s = __shfl(s, 0, 64);
  s2 = __shfl(s2, 0, 64);
  float mu = s * (1.f / 512.f);
  float var = s2 * (1.f / 512.f) - mu * mu;
  float rstd = rsqrtf(var + 1e-5f);
  float y[8];
#pragma unroll
  for (int i = 0; i < 8; ++i) {
    int e = lane + 64 * i;
    y[i] = (v[i] - mu) * rstd * g[e] + bt[e];
  }
  for (int l = 0; l < LL; ++l) {
    float p = 0.f;
#pragma unroll
    for (int i = 0; i < 8; ++i) p += y[i] * W[(size_t)l * 512 + lane + 64 * i];
#pragma unroll
    for (int off = 32; off; off >>= 1) p += __shfl_down(p, off, 64);
    if (lane == 0) out[(size_t)row * LL + l] = p + lb[l];
  }
}

// ---------------------------------------------------------------------------
// CRF numerator + denominator + loss. One block of 256 threads.
__global__ __launch_bounds__(256) void crf_kernel(
    const float* __restrict__ logits, const int* __restrict__ labels,
    const int* __restrict__ mask, const float* __restrict__ cs,
    const float* __restrict__ ce, const float* __restrict__ ct,
    float* __restrict__ loss_out) {
  __shared__ float trans[9][12];
  __shared__ float alpha[2][BB][12];
  __shared__ float numsh[BB];
  __shared__ float res[BB];
  int tid = threadIdx.x;
  int b = tid >> 4;
  int i = tid & 15;
  if (tid < 81) trans[tid / 9][tid % 9] = ct[tid];
  __syncthreads();
  const float* lg = logits + (size_t)b * SS * LL;
  const int* lbp = labels + (size_t)b * SS;
  const int* mk = mask + (size_t)b * SS;

  float np = 0.f;
  int msum = 0;
  for (int t = i; t < SS; t += 16) {
    msum += mk[t];
    if (t == 0) {
      int l0 = lbp[0];
      np += cs[l0] + lg[l0];
    } else {
      float m = (float)mk[t];
      np += (trans[lbp[t - 1]][lbp[t]] + lg[(size_t)t * LL + lbp[t]]) * m;
    }
  }
#pragma unroll
  for (int off = 8; off; off >>= 1) {
    np += __shfl_down(np, off, 16);
    msum += __shfl_down(msum, off, 16);
  }
  if (i == 0) {
    int last = msum - 1;
    numsh[b] = np + ce[lbp[last]];
  }

  if (i < LL) alpha[0][b][i] = cs[i] + lg[i];
  int cur = 0;
  for (int t = 1; t < SS; ++t) {
    if (i < LL) {
      float e = lg[(size_t)t * LL + i];
      float av[9];
      float mmax = -1e30f;
#pragma unroll
      for (int p = 0; p < LL; ++p) {
        float vv = alpha[cur][b][p] + trans[p][i];
        av[p] = vv;
        mmax = fmaxf(mmax, vv);
      }
      float ssum = 0.f;
#pragma unroll
      for (int p = 0; p < LL; ++p) ssum += __expf(av[p] - mmax);
      float anew = e + mmax + logf(ssum);
      float aold = alpha[cur][b][i];
      alpha[cur ^ 1][b][i] = (mk[t] > 0) ? anew : aold;
    }
    cur ^= 1;
  }
  if (i == 0) {
    float arr[9];
    float m2 = -1e30f;
#pragma unroll
    for (int cc = 0; cc < LL; ++cc) {
      arr[cc] = alpha[cur][b][cc] + ce[cc];
      m2 = fmaxf(m2, arr[cc]);
    }
    float ssd = 0.f;
#pragma unroll
    for (int cc = 0; cc < LL; ++cc) ssd += __expf(arr[cc] - m2);
    float denom = m2 + logf(ssd);
    res[b] = numsh[b] - denom;
  }
  __syncthreads();
  if (tid == 0) {
    float Lsum = 0.f;
    for (int b2 = 0; b2 < BB; ++b2) Lsum += res[b2];
    loss_out[0] = -Lsum;
  }
}

// ---------------------------------------------------------------------------
extern "C" void kernel_launch(void* const* d_in, const int* in_sizes, int n_in,
                              void* d_out, int out_size, void* d_ws, size_t ws_size,
                              hipStream_t stream) {
  const int* input_ids = (const int*)d_in[0];
  const int* attn_mask = (const int*)d_in[1];
  const int* labels = (const int*)d_in[2];
  const float* embedding = (const float*)d_in[3];
  const float* w_ih_l0 = (const float*)d_in[4];
  const float* w_ih_rest = (const float*)d_in[5];
  const float* w_hh = (const float*)d_in[6];
  const float* bvec = (const float*)d_in[7];
  const float* ln_g = (const float*)d_in[8];
  const float* ln_b = (const float*)d_in[9];
  const float* lin_w = (const float*)d_in[10];
  const float* lin_b = (const float*)d_in[11];
  const float* crf_start = (const float*)d_in[12];
  const float* crf_end = (const float*)d_in[13];
  const float* crf_trans = (const float*)d_in[14];
  float* out = (float*)d_out;
  char* base = (char*)d_ws;

  unsigned short* x0    = (unsigned short*)(base);                        // 2 MB
  unsigned short* xoutA = (unsigned short*)(base + (2u << 20));           // 4 MB
  unsigned short* xoutB = (unsigned short*)(base + (6u << 20));           // 4 MB
  unsigned short* xgP   = (unsigned short*)(base + (10u << 20));          // 16 MB
  unsigned*       wfrag = (unsigned*)(base + (26u << 20));                // 2 MB
  float*          biasPF= (float*)(base + (28u << 20));                   // 32 KB
  unsigned short* wihP  = (unsigned short*)(base + (29u << 20));          // 7 MB

  embed_bf16<<<ROWS, 256, 0, stream>>>(input_ids, embedding, x0);
  pack_whh_mx<<<dim3(64, 2, 8), 64, 0, stream>>>(w_hh, wfrag);
  bias_perm<<<32, 256, 0, stream>>>(bvec, biasPF);
  prep_wih<<<dim3(4096, 1, 4), 256, 0, stream>>>(w_ih_l0, w_ih_rest, wihP, nullptr);

  // wihP per-layer offsets (ushorts): l0=0, l1=524288, l2=1572864, l3=2621440
  const size_t WOFF[4] = {0, 524288, 1572864, 2621440};

  const unsigned short* cur = x0;
  unsigned short* nxt = xoutA;
  for (int l = 0; l < 4; ++l) {
    int K = l ? 512 : 256;
    gemm_xg128<<<dim3(8, 32, 2), 512, 0, stream>>>(
        cur, K, wihP + WOFF[l], biasPF + (size_t)l * 2048, xgP);
    lstm_mx<<<8, 1024, 0, stream>>>(xgP, wfrag + (size_t)l * 131072, nxt);
    cur = nxt;
    nxt = (nxt == xoutA) ? xoutB : xoutA;
  }

  ln_logits<<<ROWS, 64, 0, stream>>>(cur, ln_g, ln_b, lin_w, lin_b, out);
  crf_kernel<<<1, 256, 0, stream>>>(out, labels, attn_mask, crf_start, crf_end,
                                    crf_trans, out + (size_t)ROWS * LL);
}

// Round 7
// 993.209 us; speedup vs baseline: 1.0526x; 1.0074x over previous
//
#include <hip/hip_runtime.h>
#include <math.h>
#include <stdint.h>

// Problem constants: B=16, S=256, E=256, H=256, V=50000, L=9
#define BB 16
#define SS 256
#define LL 9
#define ROWS 4096
#define HP 272         // bytes per batch row of H in LDS (fp8)

typedef __attribute__((ext_vector_type(8))) short short8;   // 8 bf16
typedef __attribute__((ext_vector_type(4))) float f32x4;    // MFMA acc
typedef __attribute__((ext_vector_type(8))) int i32x8;      // 32B MX fragment

#define HSCALE 256.0f
#define LOG2E  1.44269504f
// per-gate weight pack constants: i,f,o = -LOG2E*1024; g = +2*LOG2E*512
#define WCONST 1477.3199f
#define SCALE_ONE 0x7F7F7F7Fu
#define SCALE_IFO 0x6D6D6D6Du
#define SCALE_G   0x6E6E6E6Eu

__device__ __forceinline__ unsigned short f2bf(float f) {
  unsigned u = __float_as_uint(f);
  return (unsigned short)((u + 0x7FFF + ((u >> 16) & 1)) >> 16);  // RNE
}
__device__ __forceinline__ float bf2f(unsigned short s) {
  return __uint_as_float(((unsigned)s) << 16);
}

// async global->LDS, 16B per lane; LDS dest = (wave-uniform base) + lane*16
__device__ __forceinline__ void gl2lds16(const void* g, void* l) {
  __builtin_amdgcn_global_load_lds(
      (const __attribute__((address_space(1))) void*)g,
      (__attribute__((address_space(3))) void*)l, 16, 0, 0);
}

// LDS-only barrier: drains DS ops (lgkmcnt) but NOT global stores/loads
// (vmcnt). Measured neutral vs __syncthreads (R4 == R1); kept. Trailing
// memory-clobber keeps next step's ds_read below the barrier without
// pinning VALU scheduling (sched_barrier(0) cost 230 cyc/step in R2).
__device__ __forceinline__ void barrier_lds_only() {
  asm volatile("s_waitcnt lgkmcnt(0)" ::: "memory");
  __builtin_amdgcn_s_barrier();
  asm volatile("" ::: "memory");
}

// ---------------------------------------------------------------------------
// Fused preprocessing: embed | prep_wih | pack_whh | bias_perm as disjoint
// blockIdx segments (all independent; one dispatch instead of four).
__global__ __launch_bounds__(256) void prep_all(
    const int* __restrict__ ids, const float* __restrict__ emb,
    unsigned short* __restrict__ x0,
    const float* __restrict__ w_l0, const float* __restrict__ w_rest,
    unsigned short* __restrict__ wp,
    const float* __restrict__ whh, unsigned* __restrict__ wfrag,
    const float* __restrict__ b2, float* __restrict__ biasPF) {
  int bid = blockIdx.x;
  int tid = threadIdx.x;

  if (bid < 4096) {
    // ---- embed: gather -> bf16 x0 [4096][256]
    int id = ids[bid];
    x0[(size_t)bid * 256 + tid] = f2bf(emb[(size_t)id * 256 + tid]);
    return;
  }
  bid -= 4096;

  if (bid < 16384) {
    // ---- prep_wih: l = bid>>12, bx = bid&4095
    int l = bid >> 12;
    int bx = bid & 4095;
    int Ksh = l ? 9 : 8;
    int K = 1 << Ksh;
    long total = (long)2 * 1024 * K;
    long idx = (long)bx * 256 + tid;
    if (idx >= total) return;
    int k = (int)(idx & (K - 1));
    long r = idx >> Ksh;
    int np = (int)(r & 1023), dir = (int)(r >> 10);
    int nph = ((np & 3) << 8) + (np >> 2);
    float cg = ((np & 3) == 2) ? (2.0f * LOG2E) : (-LOG2E);
    const float* src = l ? (w_rest + (size_t)(l - 1) * 2 * 1024 * 512) : w_l0;
    size_t off = l ? (524288 + (size_t)(l - 1) * 1048576) : 0;
    wp[off + idx] = f2bf(src[((size_t)dir * 1024 + nph) * K + k] * cg);
    return;
  }
  bid -= 16384;

  if (bid < 256) {
    // ---- pack_whh: 4 (z,ks2,nb) units per block, 64 lanes each
    int u = bid * 4 + (tid >> 6);       // 0..1023
    int lane = tid & 63;
    int z = u >> 7;                      // 0..7 = layer*2+dir
    int rr = u & 127;
    int ks2 = rr >> 6;                   // 0..1
    int nb = rr & 63;                    // 0..63
    int qq = lane >> 4, col = lane & 15;
    int g = nb >> 4;
    float csc = (g == 2) ? WCONST : -WCONST;
    const float* wpp = whh + (size_t)z * 1024 * 256 +
                       (size_t)(nb * 16 + col) * 256 + ks2 * 128 + qq * 32;
    unsigned* op = wfrag + (((size_t)(z * 64 + nb) * 2 + ks2) * 64 + lane) * 8;
#pragma unroll
    for (int uu = 0; uu < 8; ++uu) {
      float v0 = wpp[uu * 4 + 0] * csc, v1 = wpp[uu * 4 + 1] * csc;
      float v2 = wpp[uu * 4 + 2] * csc, v3 = wpp[uu * 4 + 3] * csc;
      unsigned pk = __builtin_amdgcn_cvt_pk_fp8_f32(v0, v1, 0, false);
      pk = __builtin_amdgcn_cvt_pk_fp8_f32(v2, v3, pk, true);
      op[uu] = pk;
    }
    return;
  }
  bid -= 256;

  // ---- bias_perm: 32 blocks
  int i = bid * 256 + tid;  // 0..8191
  int l = i >> 11, r = i & 2047;
  int dir = r >> 10, np = r & 1023;
  int n = ((np & 3) << 8) + (np >> 2);
  float cg = ((np & 3) == 2) ? (2.0f * LOG2E) : (-LOG2E);
  biasPF[i] = (b2[l * 4096 + dir * 2048 + n] + b2[l * 4096 + dir * 2048 + 1024 + n]) * cg;
}

// ---------------------------------------------------------------------------
// bf16 MFMA GEMM, 2-phase pipeline, COALESCED epilogue (R7): C-tile staged
// through the same 32 KB LDS used by the A/B double-buffers, then written
// as 16B/lane contiguous short8 stores (4 store insts/thread vs 32
// scattered 2B stores before).
// xgP[dir][row][n'] = sum_k A[row][k]*BP[dir][n'][k] + biasPF  (cg pre-folded)
// Block 512 thr (8 waves), tile M128 x N128, BK=32, 2 blocks/CU.
__global__ __launch_bounds__(512) void gemm_xg128(
    const unsigned short* __restrict__ A, int K,
    const unsigned short* __restrict__ BP,
    const float* __restrict__ biasPF,
    unsigned short* __restrict__ xgP) {
  int dir = blockIdx.z;
  int n0 = blockIdx.x * 128, m0 = blockIdx.y * 128;
  int tid = threadIdx.x;
  int wv = tid >> 6, lane = tid & 63, quad = lane >> 4, col = lane & 15;
  // Ls layout during K-loop: [0,8192) = As[2][4096], [8192,16384) = Bs[2][4096]
  // Ls layout in epilogue:   C-tile [128 rows][128 np] bf16
  __shared__ unsigned short Ls[16384];
  const unsigned short* Bw = BP + (size_t)dir * 1024 * K;

  // staging: wave wv stages rows [16wv,16wv+16) of A and B; lane -> (row,kc)
  int srow = lane >> 2;
  int scol = (lane & 3) * 8;
  const unsigned short* ga = A + (size_t)(m0 + wv * 16 + srow) * K + scol;
  const unsigned short* gb = Bw + (size_t)(n0 + wv * 16 + srow) * K + scol;
  int lofs = wv * 512;   // wave-uniform LDS slice (1 KB)

  int wm = wv & 1;       // M 64-half
  int wn = wv >> 1;      // N 32-slice
  f32x4 acc[4][2];
#pragma unroll
  for (int mt = 0; mt < 4; ++mt)
#pragma unroll
    for (int nt = 0; nt < 2; ++nt) acc[mt][nt] = (f32x4){0.f, 0.f, 0.f, 0.f};

  int nIter = K >> 5;
  // prologue: stage tile 0 into buffer 0
  gl2lds16(ga, &Ls[lofs]);              // As buf0
  gl2lds16(gb, &Ls[8192 + lofs]);       // Bs buf0
  ga += 32; gb += 32;
  __syncthreads();               // vmcnt(0) drain + join: buf0 ready

  for (int it = 0; it < nIter; ++it) {
    int cb = it & 1;
    if (it + 1 < nIter) {        // stage next tile first: DMA overlaps compute
      gl2lds16(ga, &Ls[(cb ^ 1) * 4096 + lofs]);
      gl2lds16(gb, &Ls[8192 + (cb ^ 1) * 4096 + lofs]);
      ga += 32; gb += 32;
    }
    const unsigned short* Ab = &Ls[cb * 4096];
    const unsigned short* Bb = &Ls[8192 + cb * 4096];
    short8 bf0 = *(const short8*)&Bb[(wn * 32 + col) * 32 + quad * 8];
    short8 bf1 = *(const short8*)&Bb[(wn * 32 + 16 + col) * 32 + quad * 8];
#pragma unroll
    for (int mt = 0; mt < 4; ++mt) {
      short8 af = *(const short8*)&Ab[(wm * 64 + mt * 16 + col) * 32 + quad * 8];
      acc[mt][0] = __builtin_amdgcn_mfma_f32_16x16x32_bf16(af, bf0, acc[mt][0], 0, 0, 0);
      acc[mt][1] = __builtin_amdgcn_mfma_f32_16x16x32_bf16(af, bf1, acc[mt][1], 0, 0, 0);
    }
    __syncthreads();             // next-buf stage complete; cur-buf reads done
  }

  // ---- epilogue: stage C (bias folded, bf16) into Ls, then coalesced write
#pragma unroll
  for (int nt = 0; nt < 2; ++nt) {
    int npl = wn * 32 + nt * 16 + col;
    float bia = biasPF[dir * 1024 + n0 + npl];
#pragma unroll
    for (int mt = 0; mt < 4; ++mt)
#pragma unroll
      for (int r = 0; r < 4; ++r)
        Ls[(wm * 64 + mt * 16 + quad * 4 + r) * 128 + npl] =
            f2bf(acc[mt][nt][r] + bia);
  }
  __syncthreads();
  unsigned short* od = xgP + (size_t)dir * ROWS * 1024;
#pragma unroll
  for (int it = 0; it < 4; ++it) {
    int e = (it * 512 + tid) * 8;            // ushort8 granule
    int row = e >> 7, npl = e & 127;
    *(short8*)&od[(size_t)(m0 + row) * 1024 + n0 + npl] = *(const short8*)&Ls[e];
  }
}

// ---------------------------------------------------------------------------
// MX-fp8 (K=128) MFMA LSTM recurrence. (R4 version, 182.9 us measured —
// structural floor: per-step ~1714 cyc vs 1104-cyc MFMA-issue invariant.
// R2 DPP-gather, R5 acc-split and deferred-store all regressed; reverted.)
// 8 blocks x 1024 threads (16 waves, 4 waves/SIMD), 4 batches per block
// packed into M rows (4 copies each). Each wave owns 16 hidden units (one
// nb 16-col block per gate). xq injected via MFMA C-operand; xq prefetched
// 1 step ahead. Per-step LDS-only barrier. Per-lane ds_write_b8 H-write
// (conflict-free; the 524288 conflicts/dispatch are the af ds_reads'
// inherent 2-way aliasing, accepted).
__global__ __launch_bounds__(1024, 4) void lstm_mx(
    const unsigned short* __restrict__ xgP,   // [2][4096][1024] bf16 n'=j*4+g
    const unsigned* __restrict__ wfrag,       // layer slice: [2][64][2][64][8] dw
    unsigned short* __restrict__ xout) {      // [4096][512] bf16
  int dir = blockIdx.x & 1;
  int bg = blockIdx.x >> 1;            // 0..3 -> batches bg*4 .. bg*4+3
  int tid = threadIdx.x;
  int wv = tid >> 6, lane = tid & 63;
  int quad = lane >> 4, col = lane & 15;

  __shared__ __align__(16) unsigned char Hfrag[2][4 * HP];

  {
    // zero Hfrag[0] (4*HP = 1088 B = 272 ints)
    int* hz = (int*)&Hfrag[0][0];
    for (int i = tid; i < HP; i += 1024) hz[i] = 0;
  }

  // weight fragments: wave wv covers nb = g*16 + wv (16 hidden units x 4 gates)
  i32x8 wf[4][2];
#pragma unroll
  for (int g = 0; g < 4; ++g) {
    int nb = g * 16 + wv;
#pragma unroll
    for (int ks2 = 0; ks2 < 2; ++ks2)
      wf[g][ks2] = *(const i32x8*)(wfrag +
          (((size_t)(dir * 64 + nb) * 2 + ks2) * 64 + lane) * 8);
  }

  // A-fragment: row = lane&15 -> batch = row>>2 (4 copies), k-chunk = quad*32
  int aoff = ((lane & 15) >> 2) * HP + (lane >> 4) * 32;

  int j = 16 * wv + col;               // this thread's hidden unit
  int b = bg * 4 + quad;               // this thread's batch
  int pos0 = dir ? (SS - 1) : 0;
  int dstep = dir ? -1 : 1;
  const unsigned short* xq_ptr =
      xgP + ((size_t)dir * ROWS + (size_t)b * SS + pos0) * 1024 + j * 4;
  unsigned short* xo_ptr = xout + ((size_t)b * SS + pos0) * 512 + dir * 256 + j;
  int xq_d = dstep * 1024;
  int xo_d = dstep * 512;
  int hw = quad * HP + j;              // this thread's H byte slot

  float Cp = 0.f;                 // C' = 2*LOG2E * c
  int cur = 0;
  // prefetch step 0 gate inputs
  ushort4 xq_n = *(const ushort4*)xq_ptr;
  xq_ptr += xq_d;
  __syncthreads();                // initial full sync (zero-init visible)

  for (int t = 0; t < SS; ++t) {
    ushort4 xq = xq_n;
    // prefetch t+1 (t=255 over-read stays inside the 16 MB xgP; value unused)
    xq_n = *(const ushort4*)xq_ptr;
    xq_ptr += xq_d;

    i32x8 af0 = *(const i32x8*)&Hfrag[cur][aoff];
    i32x8 af1 = *(const i32x8*)&Hfrag[cur][aoff + 128];

    // inject xq via C-operand: lane's acc[g][0] is exactly (row=quad*4, col)
    f32x4 acc[4];
    acc[0] = (f32x4){bf2f(xq.x), 0.f, 0.f, 0.f};
    acc[1] = (f32x4){bf2f(xq.y), 0.f, 0.f, 0.f};
    acc[2] = (f32x4){bf2f(xq.z), 0.f, 0.f, 0.f};
    acc[3] = (f32x4){bf2f(xq.w), 0.f, 0.f, 0.f};
#pragma unroll
    for (int g = 0; g < 4; ++g) {
      unsigned sb = (g == 2) ? SCALE_G : SCALE_IFO;
      acc[g] = __builtin_amdgcn_mfma_scale_f32_16x16x128_f8f6f4(
          af0, wf[g][0], acc[g], 0, 0, 0, SCALE_ONE, 0, sb);
      acc[g] = __builtin_amdgcn_mfma_scale_f32_16x16x128_f8f6f4(
          af1, wf[g][1], acc[g], 0, 0, 0, SCALE_ONE, 0, sb);
    }

    int nxt = cur ^ 1;
    float gi = acc[0][0];
    float gf = acc[1][0];
    float gt = acc[2][0];
    float go = acc[3][0];
    float si = __builtin_amdgcn_rcpf(1.0f + __builtin_amdgcn_exp2f(gi));
    float sf = __builtin_amdgcn_rcpf(1.0f + __builtin_amdgcn_exp2f(gf));
    float so = __builtin_amdgcn_rcpf(1.0f + __builtin_amdgcn_exp2f(go));
    float rg = __builtin_amdgcn_rcpf(1.0f + __builtin_amdgcn_exp2f(gt));
    float tg2 = fmaf(-4.0f * LOG2E, rg, 2.0f * LOG2E);
    Cp = fmaf(sf, Cp, si * tg2);
    float rc = __builtin_amdgcn_rcpf(1.0f + __builtin_amdgcn_exp2f(Cp));
    float h = so * fmaf(-2.0f, rc, 1.0f);

    // H to LDS (critical path: ds_write -> lgkm -> barrier), then the
    // fire-and-forget global h out (never drained by the per-step barrier).
    unsigned pk = __builtin_amdgcn_cvt_pk_fp8_f32(h * HSCALE, h * HSCALE, 0, false);
    Hfrag[nxt][hw] = (unsigned char)(pk & 0xFF);
    *xo_ptr = f2bf(h);
    xo_ptr += xo_d;

    barrier_lds_only();
    cur = nxt;
  }
}

// ---------------------------------------------------------------------------
// LayerNorm + 9-way linear. One wave per row, 4 rows per block (fewer
// dispatched blocks than 4096x64; algorithm unchanged). X is bf16 [4096][512].
__global__ __launch_bounds__(256) void ln_logits(
    const unsigned short* __restrict__ X, const float* __restrict__ g,
    const float* __restrict__ bt, const float* __restrict__ W,
    const float* __restrict__ lb, float* __restrict__ out) {
  int row = blockIdx.x * 4 + (threadIdx.x >> 6);
  int lane = threadIdx.x & 63;
  const unsigned short* x = X + (size_t)row * 512;
  float v[8];
  float s = 0.f, s2 = 0.f;
#pragma unroll
  for (int i = 0; i < 8; ++i) {
    v[i] = bf2f(x[lane + 64 * i]);
    s += v[i];
    s2 += v[i] * v[i];
  }
#pragma unroll
  for (int off = 32; off; off >>= 1) {
    s += __shfl_down(s, off, 64);
    s2 += __shfl_down(s2, off, 64);
  }
  s = __shfl(s, 0, 64);
  s2 = __shfl(s2, 0, 64);
  float mu = s * (1.f / 512.f);
  float var = s2 * (1.f / 512.f) - mu * mu;
  float rstd = rsqrtf(var + 1e-5f);
  float y[8];
#pragma unroll
  for (int i = 0; i < 8; ++i) {
    int e = lane + 64 * i;
    y[i] = (v[i] - mu) * rstd * g[e] + bt[e];
  }
  for (int l = 0; l < LL; ++l) {
    float p = 0.f;
#pragma unroll
    for (int i = 0; i < 8; ++i) p += y[i] * W[(size_t)l * 512 + lane + 64 * i];
#pragma unroll
    for (int off = 32; off; off >>= 1) p += __shfl_down(p, off, 64);
    if (lane == 0) out[(size_t)row * LL + l] = p + lb[l];
  }
}

// ---------------------------------------------------------------------------
// CRF numerator + denominator + loss. One block of 256 threads.
__global__ __launch_bounds__(256) void crf_kernel(
    const float* __restrict__ logits, const int* __restrict__ labels,
    const int* __restrict__ mask, const float* __restrict__ cs,
    const float* __restrict__ ce, const float* __restrict__ ct,
    float* __restrict__ loss_out) {
  __shared__ float trans[9][12];
  __shared__ float alpha[2][BB][12];
  __shared__ float numsh[BB];
  __shared__ float res[BB];
  int tid = threadIdx.x;
  int b = tid >> 4;
  int i = tid & 15;
  if (tid < 81) trans[tid / 9][tid % 9] = ct[tid];
  __syncthreads();
  const float* lg = logits + (size_t)b * SS * LL;
  const int* lbp = labels + (size_t)b * SS;
  const int* mk = mask + (size_t)b * SS;

  float np = 0.f;
  int msum = 0;
  for (int t = i; t < SS; t += 16) {
    msum += mk[t];
    if (t == 0) {
      int l0 = lbp[0];
      np += cs[l0] + lg[l0];
    } else {
      float m = (float)mk[t];
      np += (trans[lbp[t - 1]][lbp[t]] + lg[(size_t)t * LL + lbp[t]]) * m;
    }
  }
#pragma unroll
  for (int off = 8; off; off >>= 1) {
    np += __shfl_down(np, off, 16);
    msum += __shfl_down(msum, off, 16);
  }
  if (i == 0) {
    int last = msum - 1;
    numsh[b] = np + ce[lbp[last]];
  }

  if (i < LL) alpha[0][b][i] = cs[i] + lg[i];
  int cur = 0;
  for (int t = 1; t < SS; ++t) {
    if (i < LL) {
      float e = lg[(size_t)t * LL + i];
      float av[9];
      float mmax = -1e30f;
#pragma unroll
      for (int p = 0; p < LL; ++p) {
        float vv = alpha[cur][b][p] + trans[p][i];
        av[p] = vv;
        mmax = fmaxf(mmax, vv);
      }
      float ssum = 0.f;
#pragma unroll
      for (int p = 0; p < LL; ++p) ssum += __expf(av[p] - mmax);
      float anew = e + mmax + logf(ssum);
      float aold = alpha[cur][b][i];
      alpha[cur ^ 1][b][i] = (mk[t] > 0) ? anew : aold;
    }
    cur ^= 1;
  }
  if (i == 0) {
    float arr[9];
    float m2 = -1e30f;
#pragma unroll
    for (int cc = 0; cc < LL; ++cc) {
      arr[cc] = alpha[cur][b][cc] + ce[cc];
      m2 = fmaxf(m2, arr[cc]);
    }
    float ssd = 0.f;
#pragma unroll
    for (int cc = 0; cc < LL; ++cc) ssd += __expf(arr[cc] - m2);
    float denom = m2 + logf(ssd);
    res[b] = numsh[b] - denom;
  }
  __syncthreads();
  if (tid == 0) {
    float Lsum = 0.f;
    for (int b2 = 0; b2 < BB; ++b2) Lsum += res[b2];
    loss_out[0] = -Lsum;
  }
}

// ---------------------------------------------------------------------------
extern "C" void kernel_launch(void* const* d_in, const int* in_sizes, int n_in,
                              void* d_out, int out_size, void* d_ws, size_t ws_size,
                              hipStream_t stream) {
  const int* input_ids = (const int*)d_in[0];
  const int* attn_mask = (const int*)d_in[1];
  const int* labels = (const int*)d_in[2];
  const float* embedding = (const float*)d_in[3];
  const float* w_ih_l0 = (const float*)d_in[4];
  const float* w_ih_rest = (const float*)d_in[5];
  const float* w_hh = (const float*)d_in[6];
  const float* bvec = (const float*)d_in[7];
  const float* ln_g = (const float*)d_in[8];
  const float* ln_b = (const float*)d_in[9];
  const float* lin_w = (const float*)d_in[10];
  const float* lin_b = (const float*)d_in[11];
  const float* crf_start = (const float*)d_in[12];
  const float* crf_end = (const float*)d_in[13];
  const float* crf_trans = (const float*)d_in[14];
  float* out = (float*)d_out;
  char* base = (char*)d_ws;

  unsigned short* x0    = (unsigned short*)(base);                        // 2 MB
  unsigned short* xoutA = (unsigned short*)(base + (2u << 20));           // 4 MB
  unsigned short* xoutB = (unsigned short*)(base + (6u << 20));           // 4 MB
  unsigned short* xgP   = (unsigned short*)(base + (10u << 20));          // 16 MB
  unsigned*       wfrag = (unsigned*)(base + (26u << 20));                // 2 MB
  float*          biasPF= (float*)(base + (28u << 20));                   // 32 KB
  unsigned short* wihP  = (unsigned short*)(base + (29u << 20));          // 7 MB

  // fused preprocessing: embed(4096) | prep_wih(16384) | pack_whh(256) |
  // bias_perm(32) = 20768 blocks, one dispatch
  prep_all<<<20768, 256, 0, stream>>>(input_ids, embedding, x0,
                                      w_ih_l0, w_ih_rest, wihP,
                                      w_hh, wfrag, bvec, biasPF);

  // wihP per-layer offsets (ushorts): l0=0, l1=524288, l2=1572864, l3=2621440
  const size_t WOFF[4] = {0, 524288, 1572864, 2621440};

  const unsigned short* cur = x0;
  unsigned short* nxt = xoutA;
  for (int l = 0; l < 4; ++l) {
    int K = l ? 512 : 256;
    gemm_xg128<<<dim3(8, 32, 2), 512, 0, stream>>>(
        cur, K, wihP + WOFF[l], biasPF + (size_t)l * 2048, xgP);
    lstm_mx<<<8, 1024, 0, stream>>>(xgP, wfrag + (size_t)l * 131072, nxt);
    cur = nxt;
    nxt = (nxt == xoutA) ? xoutB : xoutA;
  }

  ln_logits<<<1024, 256, 0, stream>>>(cur, ln_g, ln_b, lin_w, lin_b, out);
  crf_kernel<<<1, 256, 0, stream>>>(out, labels, attn_mask, crf_start, crf_end,
                                    crf_trans, out + (size_t)ROWS * LL);
}

// Round 8
// 985.539 us; speedup vs baseline: 1.0608x; 1.0078x over previous
//
#include <hip/hip_runtime.h>
#include <math.h>
#include <stdint.h>

// Problem constants: B=16, S=256, E=256, H=256, V=50000, L=9
#define BB 16
#define SS 256
#define LL 9
#define ROWS 4096
#define HP 272         // bytes per batch row of H in LDS (fp8)

typedef __attribute__((ext_vector_type(8))) short short8;   // 8 bf16
typedef __attribute__((ext_vector_type(4))) float f32x4;    // MFMA acc
typedef __attribute__((ext_vector_type(8))) int i32x8;      // 32B MX fragment

#define HSCALE 256.0f
#define LOG2E  1.44269504f
// per-gate weight pack constants: i,f,o = -LOG2E*1024; g = +2*LOG2E*512
#define WCONST 1477.3199f
#define SCALE_ONE 0x7F7F7F7Fu
#define SCALE_IFO 0x6D6D6D6Du
#define SCALE_G   0x6E6E6E6Eu

__device__ __forceinline__ unsigned short f2bf(float f) {
  unsigned u = __float_as_uint(f);
  return (unsigned short)((u + 0x7FFF + ((u >> 16) & 1)) >> 16);  // RNE
}
__device__ __forceinline__ float bf2f(unsigned short s) {
  return __uint_as_float(((unsigned)s) << 16);
}

// async global->LDS, 16B per lane; LDS dest = (wave-uniform base) + lane*16
__device__ __forceinline__ void gl2lds16(const void* g, void* l) {
  __builtin_amdgcn_global_load_lds(
      (const __attribute__((address_space(1))) void*)g,
      (__attribute__((address_space(3))) void*)l, 16, 0, 0);
}

// LDS-only barrier: drains DS ops (lgkmcnt) but NOT global stores/loads
// (vmcnt). Measured neutral vs __syncthreads (R4 == R1); kept. Trailing
// memory-clobber keeps next step's ds_read below the barrier without
// pinning VALU scheduling (sched_barrier(0) cost 230 cyc/step in R2).
__device__ __forceinline__ void barrier_lds_only() {
  asm volatile("s_waitcnt lgkmcnt(0)" ::: "memory");
  __builtin_amdgcn_s_barrier();
  asm volatile("" ::: "memory");
}

// ---------------------------------------------------------------------------
// Fused preprocessing: embed | prep_wih | pack_whh | bias_perm as disjoint
// blockIdx segments (all independent; one dispatch instead of four).
__global__ __launch_bounds__(256) void prep_all(
    const int* __restrict__ ids, const float* __restrict__ emb,
    unsigned short* __restrict__ x0,
    const float* __restrict__ w_l0, const float* __restrict__ w_rest,
    unsigned short* __restrict__ wp,
    const float* __restrict__ whh, unsigned* __restrict__ wfrag,
    const float* __restrict__ b2, float* __restrict__ biasPF) {
  int bid = blockIdx.x;
  int tid = threadIdx.x;

  if (bid < 4096) {
    // ---- embed: gather -> bf16 x0 [4096][256]
    int id = ids[bid];
    x0[(size_t)bid * 256 + tid] = f2bf(emb[(size_t)id * 256 + tid]);
    return;
  }
  bid -= 4096;

  if (bid < 16384) {
    // ---- prep_wih: l = bid>>12, bx = bid&4095
    int l = bid >> 12;
    int bx = bid & 4095;
    int Ksh = l ? 9 : 8;
    int K = 1 << Ksh;
    long total = (long)2 * 1024 * K;
    long idx = (long)bx * 256 + tid;
    if (idx >= total) return;
    int k = (int)(idx & (K - 1));
    long r = idx >> Ksh;
    int np = (int)(r & 1023), dir = (int)(r >> 10);
    int nph = ((np & 3) << 8) + (np >> 2);
    float cg = ((np & 3) == 2) ? (2.0f * LOG2E) : (-LOG2E);
    const float* src = l ? (w_rest + (size_t)(l - 1) * 2 * 1024 * 512) : w_l0;
    size_t off = l ? (524288 + (size_t)(l - 1) * 1048576) : 0;
    wp[off + idx] = f2bf(src[((size_t)dir * 1024 + nph) * K + k] * cg);
    return;
  }
  bid -= 16384;

  if (bid < 256) {
    // ---- pack_whh: 4 (z,ks2,nb) units per block, 64 lanes each
    int u = bid * 4 + (tid >> 6);       // 0..1023
    int lane = tid & 63;
    int z = u >> 7;                      // 0..7 = layer*2+dir
    int rr = u & 127;
    int ks2 = rr >> 6;                   // 0..1
    int nb = rr & 63;                    // 0..63
    int qq = lane >> 4, col = lane & 15;
    int g = nb >> 4;
    float csc = (g == 2) ? WCONST : -WCONST;
    const float* wpp = whh + (size_t)z * 1024 * 256 +
                       (size_t)(nb * 16 + col) * 256 + ks2 * 128 + qq * 32;
    unsigned* op = wfrag + (((size_t)(z * 64 + nb) * 2 + ks2) * 64 + lane) * 8;
#pragma unroll
    for (int uu = 0; uu < 8; ++uu) {
      float v0 = wpp[uu * 4 + 0] * csc, v1 = wpp[uu * 4 + 1] * csc;
      float v2 = wpp[uu * 4 + 2] * csc, v3 = wpp[uu * 4 + 3] * csc;
      unsigned pk = __builtin_amdgcn_cvt_pk_fp8_f32(v0, v1, 0, false);
      pk = __builtin_amdgcn_cvt_pk_fp8_f32(v2, v3, pk, true);
      op[uu] = pk;
    }
    return;
  }
  bid -= 256;

  // ---- bias_perm: 32 blocks
  int i = bid * 256 + tid;  // 0..8191
  int l = i >> 11, r = i & 2047;
  int dir = r >> 10, np = r & 1023;
  int n = ((np & 3) << 8) + (np >> 2);
  float cg = ((np & 3) == 2) ? (2.0f * LOG2E) : (-LOG2E);
  biasPF[i] = (b2[l * 4096 + dir * 2048 + n] + b2[l * 4096 + dir * 2048 + 1024 + n]) * cg;
}

// ---------------------------------------------------------------------------
// bf16 MFMA GEMM, 2-phase pipeline, coalesced LDS-staged epilogue.
// xgP[dir][row][n'] = sum_k A[row][k]*BP[dir][n'][k] + biasPF  (cg pre-folded)
// Block 512 thr (8 waves), tile M128 x N128, BK=32, 2 blocks/CU.
__global__ __launch_bounds__(512) void gemm_xg128(
    const unsigned short* __restrict__ A, int K,
    const unsigned short* __restrict__ BP,
    const float* __restrict__ biasPF,
    unsigned short* __restrict__ xgP) {
  int dir = blockIdx.z;
  int n0 = blockIdx.x * 128, m0 = blockIdx.y * 128;
  int tid = threadIdx.x;
  int wv = tid >> 6, lane = tid & 63, quad = lane >> 4, col = lane & 15;
  // Ls layout during K-loop: [0,8192) = As[2][4096], [8192,16384) = Bs[2][4096]
  // Ls layout in epilogue:   C-tile [128 rows][128 np] bf16
  __shared__ unsigned short Ls[16384];
  const unsigned short* Bw = BP + (size_t)dir * 1024 * K;

  // staging: wave wv stages rows [16wv,16wv+16) of A and B; lane -> (row,kc)
  int srow = lane >> 2;
  int scol = (lane & 3) * 8;
  const unsigned short* ga = A + (size_t)(m0 + wv * 16 + srow) * K + scol;
  const unsigned short* gb = Bw + (size_t)(n0 + wv * 16 + srow) * K + scol;
  int lofs = wv * 512;   // wave-uniform LDS slice (1 KB)

  int wm = wv & 1;       // M 64-half
  int wn = wv >> 1;      // N 32-slice
  f32x4 acc[4][2];
#pragma unroll
  for (int mt = 0; mt < 4; ++mt)
#pragma unroll
    for (int nt = 0; nt < 2; ++nt) acc[mt][nt] = (f32x4){0.f, 0.f, 0.f, 0.f};

  int nIter = K >> 5;
  // prologue: stage tile 0 into buffer 0
  gl2lds16(ga, &Ls[lofs]);              // As buf0
  gl2lds16(gb, &Ls[8192 + lofs]);       // Bs buf0
  ga += 32; gb += 32;
  __syncthreads();               // vmcnt(0) drain + join: buf0 ready

  for (int it = 0; it < nIter; ++it) {
    int cb = it & 1;
    if (it + 1 < nIter) {        // stage next tile first: DMA overlaps compute
      gl2lds16(ga, &Ls[(cb ^ 1) * 4096 + lofs]);
      gl2lds16(gb, &Ls[8192 + (cb ^ 1) * 4096 + lofs]);
      ga += 32; gb += 32;
    }
    const unsigned short* Ab = &Ls[cb * 4096];
    const unsigned short* Bb = &Ls[8192 + cb * 4096];
    short8 bf0 = *(const short8*)&Bb[(wn * 32 + col) * 32 + quad * 8];
    short8 bf1 = *(const short8*)&Bb[(wn * 32 + 16 + col) * 32 + quad * 8];
#pragma unroll
    for (int mt = 0; mt < 4; ++mt) {
      short8 af = *(const short8*)&Ab[(wm * 64 + mt * 16 + col) * 32 + quad * 8];
      acc[mt][0] = __builtin_amdgcn_mfma_f32_16x16x32_bf16(af, bf0, acc[mt][0], 0, 0, 0);
      acc[mt][1] = __builtin_amdgcn_mfma_f32_16x16x32_bf16(af, bf1, acc[mt][1], 0, 0, 0);
    }
    __syncthreads();             // next-buf stage complete; cur-buf reads done
  }

  // ---- epilogue: stage C (bias folded, bf16) into Ls, then coalesced write
#pragma unroll
  for (int nt = 0; nt < 2; ++nt) {
    int npl = wn * 32 + nt * 16 + col;
    float bia = biasPF[dir * 1024 + n0 + npl];
#pragma unroll
    for (int mt = 0; mt < 4; ++mt)
#pragma unroll
      for (int r = 0; r < 4; ++r)
        Ls[(wm * 64 + mt * 16 + quad * 4 + r) * 128 + npl] =
            f2bf(acc[mt][nt][r] + bia);
  }
  __syncthreads();
  unsigned short* od = xgP + (size_t)dir * ROWS * 1024;
#pragma unroll
  for (int it = 0; it < 4; ++it) {
    int e = (it * 512 + tid) * 8;            // ushort8 granule
    int row = e >> 7, npl = e & 127;
    *(short8*)&od[(size_t)(m0 + row) * 1024 + n0 + npl] = *(const short8*)&Ls[e];
  }
}

// ---------------------------------------------------------------------------
// MX-fp8 (K=128) MFMA LSTM recurrence. (R4 version, 182.9 us measured —
// structural floor: per-step ~1714 cyc vs 1104-cyc MFMA-issue invariant.
// R2 DPP-gather, R5 acc-split and deferred-store all regressed; reverted.)
// 8 blocks x 1024 threads (16 waves, 4 waves/SIMD), 4 batches per block
// packed into M rows (4 copies each). Each wave owns 16 hidden units (one
// nb 16-col block per gate). xq injected via MFMA C-operand; xq prefetched
// 1 step ahead. Per-step LDS-only barrier. Per-lane ds_write_b8 H-write
// (conflict-free; the 524288 conflicts/dispatch are the af ds_reads'
// inherent 2-way aliasing, accepted).
__global__ __launch_bounds__(1024, 4) void lstm_mx(
    const unsigned short* __restrict__ xgP,   // [2][4096][1024] bf16 n'=j*4+g
    const unsigned* __restrict__ wfrag,       // layer slice: [2][64][2][64][8] dw
    unsigned short* __restrict__ xout) {      // [4096][512] bf16
  int dir = blockIdx.x & 1;
  int bg = blockIdx.x >> 1;            // 0..3 -> batches bg*4 .. bg*4+3
  int tid = threadIdx.x;
  int wv = tid >> 6, lane = tid & 63;
  int quad = lane >> 4, col = lane & 15;

  __shared__ __align__(16) unsigned char Hfrag[2][4 * HP];

  {
    // zero Hfrag[0] (4*HP = 1088 B = 272 ints)
    int* hz = (int*)&Hfrag[0][0];
    for (int i = tid; i < HP; i += 1024) hz[i] = 0;
  }

  // weight fragments: wave wv covers nb = g*16 + wv (16 hidden units x 4 gates)
  i32x8 wf[4][2];
#pragma unroll
  for (int g = 0; g < 4; ++g) {
    int nb = g * 16 + wv;
#pragma unroll
    for (int ks2 = 0; ks2 < 2; ++ks2)
      wf[g][ks2] = *(const i32x8*)(wfrag +
          (((size_t)(dir * 64 + nb) * 2 + ks2) * 64 + lane) * 8);
  }

  // A-fragment: row = lane&15 -> batch = row>>2 (4 copies), k-chunk = quad*32
  int aoff = ((lane & 15) >> 2) * HP + (lane >> 4) * 32;

  int j = 16 * wv + col;               // this thread's hidden unit
  int b = bg * 4 + quad;               // this thread's batch
  int pos0 = dir ? (SS - 1) : 0;
  int dstep = dir ? -1 : 1;
  const unsigned short* xq_ptr =
      xgP + ((size_t)dir * ROWS + (size_t)b * SS + pos0) * 1024 + j * 4;
  unsigned short* xo_ptr = xout + ((size_t)b * SS + pos0) * 512 + dir * 256 + j;
  int xq_d = dstep * 1024;
  int xo_d = dstep * 512;
  int hw = quad * HP + j;              // this thread's H byte slot

  float Cp = 0.f;                 // C' = 2*LOG2E * c
  int cur = 0;
  // prefetch step 0 gate inputs
  ushort4 xq_n = *(const ushort4*)xq_ptr;
  xq_ptr += xq_d;
  __syncthreads();                // initial full sync (zero-init visible)

  for (int t = 0; t < SS; ++t) {
    ushort4 xq = xq_n;
    // prefetch t+1 (t=255 over-read stays inside the 16 MB xgP; value unused)
    xq_n = *(const ushort4*)xq_ptr;
    xq_ptr += xq_d;

    i32x8 af0 = *(const i32x8*)&Hfrag[cur][aoff];
    i32x8 af1 = *(const i32x8*)&Hfrag[cur][aoff + 128];

    // inject xq via C-operand: lane's acc[g][0] is exactly (row=quad*4, col)
    f32x4 acc[4];
    acc[0] = (f32x4){bf2f(xq.x), 0.f, 0.f, 0.f};
    acc[1] = (f32x4){bf2f(xq.y), 0.f, 0.f, 0.f};
    acc[2] = (f32x4){bf2f(xq.z), 0.f, 0.f, 0.f};
    acc[3] = (f32x4){bf2f(xq.w), 0.f, 0.f, 0.f};
#pragma unroll
    for (int g = 0; g < 4; ++g) {
      unsigned sb = (g == 2) ? SCALE_G : SCALE_IFO;
      acc[g] = __builtin_amdgcn_mfma_scale_f32_16x16x128_f8f6f4(
          af0, wf[g][0], acc[g], 0, 0, 0, SCALE_ONE, 0, sb);
      acc[g] = __builtin_amdgcn_mfma_scale_f32_16x16x128_f8f6f4(
          af1, wf[g][1], acc[g], 0, 0, 0, SCALE_ONE, 0, sb);
    }

    int nxt = cur ^ 1;
    float gi = acc[0][0];
    float gf = acc[1][0];
    float gt = acc[2][0];
    float go = acc[3][0];
    float si = __builtin_amdgcn_rcpf(1.0f + __builtin_amdgcn_exp2f(gi));
    float sf = __builtin_amdgcn_rcpf(1.0f + __builtin_amdgcn_exp2f(gf));
    float so = __builtin_amdgcn_rcpf(1.0f + __builtin_amdgcn_exp2f(go));
    float rg = __builtin_amdgcn_rcpf(1.0f + __builtin_amdgcn_exp2f(gt));
    float tg2 = fmaf(-4.0f * LOG2E, rg, 2.0f * LOG2E);
    Cp = fmaf(sf, Cp, si * tg2);
    float rc = __builtin_amdgcn_rcpf(1.0f + __builtin_amdgcn_exp2f(Cp));
    float h = so * fmaf(-2.0f, rc, 1.0f);

    // H to LDS (critical path: ds_write -> lgkm -> barrier), then the
    // fire-and-forget global h out (never drained by the per-step barrier).
    unsigned pk = __builtin_amdgcn_cvt_pk_fp8_f32(h * HSCALE, h * HSCALE, 0, false);
    Hfrag[nxt][hw] = (unsigned char)(pk & 0xFF);
    *xo_ptr = f2bf(h);
    xo_ptr += xo_d;

    barrier_lds_only();
    cur = nxt;
  }
}

// ---------------------------------------------------------------------------
// LayerNorm + 9-way linear. One wave per row, 4 rows per block.
__global__ __launch_bounds__(256) void ln_logits(
    const unsigned short* __restrict__ X, const float* __restrict__ g,
    const float* __restrict__ bt, const float* __restrict__ W,
    const float* __restrict__ lb, float* __restrict__ out) {
  int row = blockIdx.x * 4 + (threadIdx.x >> 6);
  int lane = threadIdx.x & 63;
  const unsigned short* x = X + (size_t)row * 512;
  float v[8];
  float s = 0.f, s2 = 0.f;
#pragma unroll
  for (int i = 0; i < 8; ++i) {
    v[i] = bf2f(x[lane + 64 * i]);
    s += v[i];
    s2 += v[i] * v[i];
  }
#pragma unroll
  for (int off = 32; off; off >>= 1) {
    s += __shfl_down(s, off, 64);
    s2 += __shfl_down(s2, off, 64);
  }
  s = __shfl(s, 0, 64);
  s2 = __shfl(s2, 0, 64);
  float mu = s * (1.f / 512.f);
  float var = s2 * (1.f / 512.f) - mu * mu;
  float rstd = rsqrtf(var + 1e-5f);
  float y[8];
#pragma unroll
  for (int i = 0; i < 8; ++i) {
    int e = lane + 64 * i;
    y[i] = (v[i] - mu) * rstd * g[e] + bt[e];
  }
  for (int l = 0; l < LL; ++l) {
    float p = 0.f;
#pragma unroll
    for (int i = 0; i < 8; ++i) p += y[i] * W[(size_t)l * 512 + lane + 64 * i];
#pragma unroll
    for (int off = 32; off; off >>= 1) p += __shfl_down(p, off, 64);
    if (lane == 0) out[(size_t)row * LL + l] = p + lb[l];
  }
}

// ---------------------------------------------------------------------------
// CRF numerator + denominator + loss. One block of 256 threads.
// R8: denominator rewritten in SCALED LINEAR DOMAIN (scaled-forward):
// per 16-lane group, every lane replicates the 9-state vector a[] in
// registers (compile-time-indexed only, rule #20). Per step:
//   s_i  = sum_p a_p * exp(trans[p][i])   (9 register fmaf, no LDS)
//   a'_i = exp(e_i) * s_i; masked select keeps lane's own scalar ownA
//   broadcast via __shfl(.,p,16); branchless power-of-2 rescale with
//   C ledger (no per-step exp-of-9 / logf).
// Replaces the old ~400 cyc/step LDS+9exp+log chain with ~150 cyc/step.
__global__ __launch_bounds__(256) void crf_kernel(
    const float* __restrict__ logits, const int* __restrict__ labels,
    const int* __restrict__ mask, const float* __restrict__ cs,
    const float* __restrict__ ce, const float* __restrict__ ct,
    float* __restrict__ loss_out) {
  __shared__ float trans[9][12];
  __shared__ float numsh[BB];
  __shared__ float res[BB];
  int tid = threadIdx.x;
  int b = tid >> 4;
  int i = tid & 15;
  if (tid < 81) trans[tid / 9][tid % 9] = ct[tid];
  __syncthreads();
  const float* lg = logits + (size_t)b * SS * LL;
  const int* lbp = labels + (size_t)b * SS;
  const int* mk = mask + (size_t)b * SS;

  // ---- numerator (unchanged)
  float np = 0.f;
  int msum = 0;
  for (int t = i; t < SS; t += 16) {
    msum += mk[t];
    if (t == 0) {
      int l0 = lbp[0];
      np += cs[l0] + lg[l0];
    } else {
      float m = (float)mk[t];
      np += (trans[lbp[t - 1]][lbp[t]] + lg[(size_t)t * LL + lbp[t]]) * m;
    }
  }
#pragma unroll
  for (int off = 8; off; off >>= 1) {
    np += __shfl_down(np, off, 16);
    msum += __shfl_down(msum, off, 16);
  }
  if (i == 0) {
    int last = msum - 1;
    numsh[b] = np + ce[lbp[last]];
  }

  // ---- denominator: scaled linear-domain forward
  int ii = (i < LL) ? i : 0;           // lanes 9..15 shadow lane 0 (no diverge)
  float ETc[9];                        // lane's column: exp(trans[p][ii])
#pragma unroll
  for (int p = 0; p < LL; ++p) ETc[p] = __expf(trans[p][ii]);

  // init from t=0 (log domain), then convert to scaled linear
  float own = cs[ii] + lg[ii];
  float a[9];
#pragma unroll
  for (int p = 0; p < LL; ++p) a[p] = __shfl(own, p, 16);
  float C = a[0];
#pragma unroll
  for (int p = 1; p < LL; ++p) C = fmaxf(C, a[p]);
  float ownA = __expf(own - C);
#pragma unroll
  for (int p = 0; p < LL; ++p) a[p] = __expf(a[p] - C);

  for (int t = 1; t < SS; ++t) {
    float e = lg[(size_t)t * LL + ii];
    float s = 0.f;
#pragma unroll
    for (int p = 0; p < LL; ++p) s = fmaf(a[p], ETc[p], s);
    float an = __expf(e) * s;
    float ow = (mk[t] > 0) ? an : ownA;       // masked step keeps old state
    float na[9];
#pragma unroll
    for (int p = 0; p < LL; ++p) na[p] = __shfl(ow, p, 16);
    float M = na[0];
#pragma unroll
    for (int p = 1; p < LL; ++p) M = fmaxf(M, na[p]);
    // branchless power-of-two rescale: keep M within [2^-32, 2^64]
    float f = 1.0f, dC = 0.0f;
    if (M > 0x1p64f)       { f = 0x1p-64f; dC = 44.3614195558f; }
    else if (M < 0x1p-32f) { f = 0x1p64f;  dC = -44.3614195558f; }
    C += dC;
#pragma unroll
    for (int p = 0; p < LL; ++p) a[p] = na[p] * f;
    ownA = ow * f;
  }

  float sd = 0.f;
#pragma unroll
  for (int p = 0; p < LL; ++p) sd = fmaf(a[p], __expf(ce[p]), sd);
  float denom = C + __logf(sd);
  if (i == 0) res[b] = numsh[b] - denom;

  __syncthreads();
  if (tid == 0) {
    float Lsum = 0.f;
    for (int b2 = 0; b2 < BB; ++b2) Lsum += res[b2];
    loss_out[0] = -Lsum;
  }
}

// ---------------------------------------------------------------------------
extern "C" void kernel_launch(void* const* d_in, const int* in_sizes, int n_in,
                              void* d_out, int out_size, void* d_ws, size_t ws_size,
                              hipStream_t stream) {
  const int* input_ids = (const int*)d_in[0];
  const int* attn_mask = (const int*)d_in[1];
  const int* labels = (const int*)d_in[2];
  const float* embedding = (const float*)d_in[3];
  const float* w_ih_l0 = (const float*)d_in[4];
  const float* w_ih_rest = (const float*)d_in[5];
  const float* w_hh = (const float*)d_in[6];
  const float* bvec = (const float*)d_in[7];
  const float* ln_g = (const float*)d_in[8];
  const float* ln_b = (const float*)d_in[9];
  const float* lin_w = (const float*)d_in[10];
  const float* lin_b = (const float*)d_in[11];
  const float* crf_start = (const float*)d_in[12];
  const float* crf_end = (const float*)d_in[13];
  const float* crf_trans = (const float*)d_in[14];
  float* out = (float*)d_out;
  char* base = (char*)d_ws;

  unsigned short* x0    = (unsigned short*)(base);                        // 2 MB
  unsigned short* xoutA = (unsigned short*)(base + (2u << 20));           // 4 MB
  unsigned short* xoutB = (unsigned short*)(base + (6u << 20));           // 4 MB
  unsigned short* xgP   = (unsigned short*)(base + (10u << 20));          // 16 MB
  unsigned*       wfrag = (unsigned*)(base + (26u << 20));                // 2 MB
  float*          biasPF= (float*)(base + (28u << 20));                   // 32 KB
  unsigned short* wihP  = (unsigned short*)(base + (29u << 20));          // 7 MB

  // fused preprocessing: embed(4096) | prep_wih(16384) | pack_whh(256) |
  // bias_perm(32) = 20768 blocks, one dispatch
  prep_all<<<20768, 256, 0, stream>>>(input_ids, embedding, x0,
                                      w_ih_l0, w_ih_rest, wihP,
                                      w_hh, wfrag, bvec, biasPF);

  // wihP per-layer offsets (ushorts): l0=0, l1=524288, l2=1572864, l3=2621440
  const size_t WOFF[4] = {0, 524288, 1572864, 2621440};

  const unsigned short* cur = x0;
  unsigned short* nxt = xoutA;
  for (int l = 0; l < 4; ++l) {
    int K = l ? 512 : 256;
    gemm_xg128<<<dim3(8, 32, 2), 512, 0, stream>>>(
        cur, K, wihP + WOFF[l], biasPF + (size_t)l * 2048, xgP);
    lstm_mx<<<8, 1024, 0, stream>>>(xgP, wfrag + (size_t)l * 131072, nxt);
    cur = nxt;
    nxt = (nxt == xoutA) ? xoutB : xoutA;
  }

  ln_logits<<<1024, 256, 0, stream>>>(cur, ln_g, ln_b, lin_w, lin_b, out);
  crf_kernel<<<1, 256, 0, stream>>>(out, labels, attn_mask, crf_start, crf_end,
                                    crf_trans, out + (size_t)ROWS * LL);
}